// Round 10
// baseline (809.672 us; speedup 1.0000x reference)
//
#include <hip/hip_runtime.h>
#include <hip/hip_bf16.h>

#define B_N   16384
#define D_N   17
#define H_N   256
#define E_N   64

typedef __attribute__((ext_vector_type(8))) short bf16x8;
typedef __attribute__((ext_vector_type(4))) float f32x4;

#define WAITV(N) asm volatile("s_waitcnt vmcnt(" #N ")" ::: "memory")
#define WAITL()  asm volatile("s_waitcnt lgkmcnt(0)" ::: "memory")
#define BAR()    __builtin_amdgcn_s_barrier()

static __device__ __forceinline__ short f2bf(float f){
  unsigned u = __builtin_bit_cast(unsigned, f);
  unsigned r = (u + 0x7fffu + ((u >> 16) & 1u)) >> 16;   // RNE
  return (short)(unsigned short)r;
}
static __device__ __forceinline__ float bf2f(short s){
  unsigned u = ((unsigned)(unsigned short)s) << 16;
  return __builtin_bit_cast(float, u);
}
static __device__ __forceinline__ float lrelu(float v){ return fmaxf(v, 0.01f * v); }

// packed f32x2 -> bf16x2 (RNE), 1 instruction; src0 -> low 16, src1 -> high 16
static __device__ __forceinline__ unsigned cvtpk2(float lo, float hi){
  unsigned r;
  asm("v_cvt_pk_bf16_f32 %0, %1, %2" : "=v"(r) : "v"(lo), "v"(hi));
  return r;
}

// async global->LDS, 16B per lane. LDS dest is wave-uniform base + lane*16.
static __device__ __forceinline__ void gload_lds16(const short* g, short* l){
  __builtin_amdgcn_global_load_lds(
      (const __attribute__((address_space(1))) unsigned int*)g,
      (__attribute__((address_space(3))) unsigned int*)l, 16, 0, 0);
}

// ---------- prep: fp32 (G,R,C) -> bf16 (G,C,R) ----------
__global__ void transpose_convert(const float* __restrict__ in, short* __restrict__ outp,
                                  int R, int C){
  __shared__ float tile[32][33];
  int g = blockIdx.z;
  const float* inp = in + (size_t)g * R * C;
  short* op = outp + (size_t)g * R * C;
  int c0 = blockIdx.x * 32, r0 = blockIdx.y * 32;
  for (int i = threadIdx.y; i < 32; i += 8)
    tile[i][threadIdx.x] = inp[(size_t)(r0 + i) * C + c0 + threadIdx.x];
  __syncthreads();
  for (int i = threadIdx.y; i < 32; i += 8)
    op[(size_t)(c0 + i) * R + r0 + threadIdx.x] = f2bf(tile[threadIdx.x][i]);
}

// ---------- prep: stack+convert Wq|Wk|Wv -> bf16 [192][64] ----------
__global__ void convert_wqkv(const float* __restrict__ Wq, const float* __restrict__ Wk,
                             const float* __restrict__ Wv, short* __restrict__ outw){
  int i = blockIdx.x * 256 + threadIdx.x;        // 0..12287
  int g = i >> 12, r = i & 4095;
  const float* W = (g == 0) ? Wq : (g == 1 ? Wk : Wv);
  outw[i] = f2bf(W[r]);
}

// ---------- prep: wcomb[e] = sum_eo Wo[eo][e]*Wfc[eo]; wcomb[64] = bo.Wfc + bfc ----------
__global__ void wcomb_kernel(const float* __restrict__ Wo, const float* __restrict__ Wfc,
                             const float* __restrict__ bo, const float* __restrict__ bfc,
                             float* __restrict__ wcomb){
  int e = threadIdx.x;
  float acc = 0.f;
  for (int eo = 0; eo < 64; ++eo) acc += Wo[eo * 64 + e] * Wfc[eo];
  wcomb[e] = acc;
  if (e == 0){
    float bc = bfc[0];
    for (int eo = 0; eo < 64; ++eo) bc += bo[eo] * Wfc[eo];
    wcomb[64] = bc;
  }
}

// Weight slice staging (256-thr block). Slice kk of [256][256] bf16 = 16 KB
// = 1024 x 16B chunks, 4/thread. Chunk swizzle on the GLOBAL source address
// (gload_lds writes linearly); read XORs the same term.
static __device__ __forceinline__ void stage_w256(const short* Wt, int kk, short* wb,
                                                  int tid, int wave){
  #pragma unroll
  for (int r = 0; r < 4; ++r){
    int li = r * 256 + tid;
    int n  = li >> 2;
    int cc = (li & 3) ^ ((n >> 1) & 3);
    gload_lds16(Wt + n * 256 + kk * 32 + cc * 8,
                wb + (size_t)(r * 256 + wave * 64) * 8);
  }
}
// Full Wf matrix [64][256] = 32 KB into a contiguous region, XOR-16 row swizzle:
// LDS chunk (n, c) holds global k-chunk (c&16)|((c^n)&15).
static __device__ __forceinline__ void stage_wf_all(const short* Wfd, short* region,
                                                    int tid, int wave){
  #pragma unroll
  for (int ld = 0; ld < 8; ++ld){
    int li = ld * 256 + tid;          // 0..2047
    int n  = li >> 5;                 // row 0..63
    int c  = li & 31;
    int kc = (c & 16) | ((c ^ n) & 15);
    gload_lds16(Wfd + n * 256 + kc * 8, region + (size_t)(ld * 256 + wave * 64) * 8);
  }
}

// ---------- main subnet kernel (identical to R9 passing version) ----------
__global__ __launch_bounds__(256, 2) void subnet_kernel(
    const float* __restrict__ x, const float* __restrict__ W1, const float* __restrict__ b1,
    const float* __restrict__ bm, const float* __restrict__ bf_,
    const float* __restrict__ bq, const float* __restrict__ bk, const float* __restrict__ bv,
    const short* __restrict__ WmT, const short* __restrict__ WfT, const short* __restrict__ Wqkv,
    short* __restrict__ qkv)
{
  __shared__ short hbuf[64 * 256];       // 32 KB activations / tokens / qkv-out
  __shared__ short wbuf[3][256 * 32];    // 3 x 16 KB weight slices

  // XCD swizzle: 4352 = 8*544, d-major (per-XCD weight set L2-resident)
  int wg = blockIdx.x;
  int idx = (wg & 7) * 544 + (wg >> 3);
  const int d  = idx >> 8;
  const int m0 = (idx & 255) * 64;

  const int tid = threadIdx.x;
  const int lane = tid & 63, wave = tid >> 6;
  const int l15 = lane & 15, lhi = lane >> 4;

  const short* WtL0 = WmT + (size_t)(0 * D_N + d) * (H_N * H_N);
  const short* WtL1 = WmT + (size_t)(1 * D_N + d) * (H_N * H_N);
  const short* Wfd  = WfT + (size_t)d * (E_N * H_N);

  // prologue: slices 0,1 fly during phase 0
  stage_w256(WtL0, 0, &wbuf[0][0], tid, wave);
  stage_w256(WtL0, 1, &wbuf[1][0], tid, wave);

  // ---- phase 0: h0 = lrelu(x*W1+b1) -> swizzled LDS [m][k], cvt_pk b32 writes
  {
    const int kp = tid & 127;            // k-pair, k0 = 2*kp
    const int mh = tid >> 7;             // 0/1 -> m half
    const float w1a = W1[d * H_N + 2 * kp], w1b = W1[d * H_N + 2 * kp + 1];
    const float b1a = b1[d * H_N + 2 * kp], b1b = b1[d * H_N + 2 * kp + 1];
    #pragma unroll
    for (int i = 0; i < 32; ++i){
      int m = mh * 32 + i;
      float xv = x[(size_t)(m0 + m) * D_N + d];
      unsigned pk = cvtpk2(lrelu(xv * w1a + b1a), lrelu(xv * w1b + b1b));
      int byte = m * 512 + ((((kp >> 2) ^ (m & 7))) << 4) + ((kp & 3) << 2);
      *(unsigned*)((char*)&hbuf[0] + byte) = pk;
    }
  }
  WAITL();   // drain own h0 ds_writes; visibility via first step barrier

  // ---- 2 middle layers: (64x256)@(256x256); wave = 64-col slice; in-place
  for (int L = 0; L < 2; ++L){
    const float* bias = bm + (size_t)(L * D_N + d) * H_N;
    f32x4 acc[4][4];
    #pragma unroll
    for (int a = 0; a < 4; ++a)
      #pragma unroll
      for (int c = 0; c < 4; ++c) acc[a][c] = (f32x4){0.f, 0.f, 0.f, 0.f};

    #pragma unroll
    for (int kk = 0; kk < 8; ++kk){
      const int s = L * 8 + kk;
      if (s == 15) { WAITV(0); } else { WAITV(4); }
      BAR();
      const int s2 = s + 2;
      if (s2 < 8)       stage_w256(WtL0, s2,     &wbuf[s2 % 3][0], tid, wave);
      else if (s2 < 16) stage_w256(WtL1, s2 - 8, &wbuf[s2 % 3][0], tid, wave);
      // s2 >= 16: Wf is bulk-staged at the L1 epilogue

      const short* wb = &wbuf[s % 3][0];
      bf16x8 af[4], bfr[4];
      #pragma unroll
      for (int fr = 0; fr < 4; ++fr){
        int row = fr * 16 + l15;
        int cch = kk * 4 + lhi;
        af[fr] = *(const bf16x8*)((const char*)&hbuf[0] + row * 512 + ((cch ^ (row & 7)) << 4));
      }
      #pragma unroll
      for (int fc = 0; fc < 4; ++fc){
        int n = wave * 64 + fc * 16 + l15;
        bfr[fc] = *(const bf16x8*)((const char*)wb + n * 64 + ((lhi ^ ((n >> 1) & 3)) << 4));
      }
      #pragma unroll
      for (int fr = 0; fr < 4; ++fr)
        #pragma unroll
        for (int fc = 0; fc < 4; ++fc)
          acc[fr][fc] = __builtin_amdgcn_mfma_f32_16x16x32_bf16(af[fr], bfr[fc], acc[fr][fc], 0, 0, 0);
    }
    BAR();   // all waves done reading hbuf + wbuf
    if (L == 1) stage_wf_all(Wfd, &wbuf[1][0], tid, wave);  // 32 KB bulk; epilogue = cover
    // bias + lrelu, cvt_pk pairs, bf16 back in place
    #pragma unroll
    for (int fr = 0; fr < 4; ++fr)
      #pragma unroll
      for (int fc = 0; fc < 4; ++fc){
        int col = wave * 64 + fc * 16 + l15;
        float b = bias[col];
        float v0 = lrelu(acc[fr][fc][0] + b), v1 = lrelu(acc[fr][fc][1] + b);
        float v2 = lrelu(acc[fr][fc][2] + b), v3 = lrelu(acc[fr][fc][3] + b);
        unsigned p01 = cvtpk2(v0, v1), p23 = cvtpk2(v2, v3);
        int r0 = fr * 16 + lhi * 4;
        int cb = (col >> 3), c7 = (col & 7) << 1;
        *(short*)((char*)&hbuf[0] + (r0+0)*512 + ((cb ^ ((r0+0)&7)) << 4) + c7) = (short)(p01 & 0xffff);
        *(short*)((char*)&hbuf[0] + (r0+1)*512 + ((cb ^ ((r0+1)&7)) << 4) + c7) = (short)(p01 >> 16);
        *(short*)((char*)&hbuf[0] + (r0+2)*512 + ((cb ^ ((r0+2)&7)) << 4) + c7) = (short)(p23 & 0xffff);
        *(short*)((char*)&hbuf[0] + (r0+3)*512 + ((cb ^ ((r0+3)&7)) << 4) + c7) = (short)(p23 >> 16);
      }
    WAITL();  // drain own epilogue ds_writes; visibility via next barrier
  }

  // ---- Wf layer: (64x256)@(256x64) + bf, weights fully resident, NO inner barriers
  {
    WAITV(0);   // own Wf bulk loads landed
    BAR();      // everyone's landed; also L1 epilogue visible
    const short* wf = &wbuf[1][0];
    const int r0 = wave * 16;
    f32x4 acc[4];
    #pragma unroll
    for (int fc = 0; fc < 4; ++fc) acc[fc] = (f32x4){0.f, 0.f, 0.f, 0.f};
    #pragma unroll
    for (int kk = 0; kk < 8; ++kk){
      int row = r0 + l15;
      int cch = kk * 4 + lhi;
      bf16x8 a = *(const bf16x8*)((const char*)&hbuf[0] + row * 512 + ((cch ^ (row & 7)) << 4));
      int K = kk * 4 + lhi;
      int c = (K & 16) | ((K ^ l15) & 15);
      #pragma unroll
      for (int fc = 0; fc < 4; ++fc){
        bf16x8 b = *(const bf16x8*)((const char*)wf + (size_t)(fc * 16 + l15) * 512 + c * 16);
        acc[fc] = __builtin_amdgcn_mfma_f32_16x16x32_bf16(a, b, acc[fc], 0, 0, 0);
      }
    }
    BAR();   // all waves done reading hbuf activations before token overlay write
    #pragma unroll
    for (int fc = 0; fc < 4; ++fc){
      int col = fc * 16 + l15;
      float b = bf_[d * E_N + col];
      float v0 = acc[fc][0] + b, v1 = acc[fc][1] + b;
      float v2 = acc[fc][2] + b, v3 = acc[fc][3] + b;
      unsigned p01 = cvtpk2(v0, v1), p23 = cvtpk2(v2, v3);
      int rr = r0 + lhi * 4;
      int cb = (col >> 3), c7 = (col & 7) << 1;
      *(short*)((char*)&hbuf[0] + (rr+0)*128 + ((cb ^ ((rr+0)&7)) << 4) + c7) = (short)(p01 & 0xffff);
      *(short*)((char*)&hbuf[0] + (rr+1)*128 + ((cb ^ ((rr+1)&7)) << 4) + c7) = (short)(p01 >> 16);
      *(short*)((char*)&hbuf[0] + (rr+2)*128 + ((cb ^ ((rr+2)&7)) << 4) + c7) = (short)(p23 & 0xffff);
      *(short*)((char*)&hbuf[0] + (rr+3)*128 + ((cb ^ ((rr+3)&7)) << 4) + c7) = (short)(p23 >> 16);
    }
    WAITL();
    BAR();   // tokens visible to all waves
  }

  // ---- fused QKV: tokens(64x64) @ [Wq|Wk|Wv]^T (64x192); wave = 48-col slice
  {
    f32x4 acc[4][3];
    #pragma unroll
    for (int fr = 0; fr < 4; ++fr)
      #pragma unroll
      for (int fc = 0; fc < 3; ++fc) acc[fr][fc] = (f32x4){0.f, 0.f, 0.f, 0.f};
    #pragma unroll
    for (int kk = 0; kk < 2; ++kk){
      bf16x8 af[4];
      #pragma unroll
      for (int fr = 0; fr < 4; ++fr){
        int row = fr * 16 + l15;
        int cch = kk * 4 + lhi;
        af[fr] = *(const bf16x8*)((const char*)&hbuf[0] + row * 128 + ((cch ^ (row & 7)) << 4));
      }
      bf16x8 bb[3];
      #pragma unroll
      for (int fc = 0; fc < 3; ++fc){
        int n = wave * 48 + fc * 16 + l15;
        bb[fc] = *(const bf16x8*)(Wqkv + (size_t)n * E_N + kk * 32 + lhi * 8);
      }
      #pragma unroll
      for (int fr = 0; fr < 4; ++fr)
        #pragma unroll
        for (int fc = 0; fc < 3; ++fc)
          acc[fr][fc] = __builtin_amdgcn_mfma_f32_16x16x32_bf16(af[fr], bb[fc], acc[fr][fc], 0, 0, 0);
    }
    BAR();   // all token reads done; hbuf reusable as qkv-out staging
    // qkv-out LDS layout: [64 rows][stride 200 shorts] (row = local sample)
    #pragma unroll
    for (int fr = 0; fr < 4; ++fr)
      #pragma unroll
      for (int fc = 0; fc < 3; ++fc){
        int n = wave * 48 + fc * 16 + l15;
        int g = n >> 6, nl = n & 63;
        float bias = (g == 0) ? bq[nl] : (g == 1 ? bk[nl] : bv[nl]);
        #pragma unroll
        for (int j = 0; j < 4; ++j){
          int row = fr * 16 + lhi * 4 + j;
          float v = acc[fr][fc][j] + bias;
          hbuf[row * 200 + n] = (short)(cvtpk2(v, v) & 0xffff);
        }
      }
    WAITL();
    BAR();
    // coalesced b128 out: thread t -> row t>>2, chunks (t&3)+4*rep
    {
      int row = tid >> 2, c4 = tid & 3;
      const short* lsrc = &hbuf[0] + row * 200;
      short* gdst = qkv + ((size_t)(m0 + row) * D_N + d) * 192;
      #pragma unroll
      for (int rep = 0; rep < 6; ++rep){
        int c = c4 + rep * 4;
        bf16x8 v = *(const bf16x8*)(lsrc + c * 8);
        *(bf16x8*)(gdst + c * 8) = v;
      }
    }
  }
}

// ---------- attention + pool + folded head: one wave per sample ----------
// R9 lesson: the unrolled t-loop + s[17]/q[16]/wvec[16] arrays spilled to
// scratch (FETCH 436MB / WRITE 770MB, VALUBusy 8%). This version has NO
// spillable state: fused exp-sum softmax (no s[17], no max pass -- scores
// are O(1), fp32 exp safe; exp(s)/sum(exp(s)) == stabilized softmax), wc[]
// read transiently, and the t-loop is explicitly NOT unrolled.
__global__ __launch_bounds__(256, 4) void attn_kernel(
    const short* __restrict__ qkv, const float* __restrict__ wc, float* __restrict__ out)
{
  __shared__ short smem[4][17 * 192];     // per-wave sample tile, XOR-swizzled 16B chunks
  const int tid = threadIdx.x, lane = tid & 63, wave = tid >> 6;
  const int h = lane >> 4, iq = lane & 15;

  const int b = blockIdx.x * 4 + wave;
  const short* src = qkv + (size_t)b * (17 * 192);
  for (int g0 = lane; g0 < 408; g0 += 64){
    int i = g0 / 24, c = g0 % 24;
    bf16x8 v = *(const bf16x8*)(src + g0 * 8);
    *(bf16x8*)((char*)&smem[wave][0] + i * 384 + ((c ^ (i & 7)) << 4)) = v;
  }
  // same-wave LDS RAW is in-order; compiler inserts lgkmcnt waits before uses

  // pre-dot: vtilde_j = v_j . wcomb (head h slice). Lane holds j = iq;
  // j = 16 computed redundantly by every lane (lane-local, no shuffle).
  float vt = 0.f, vt16 = 0.f;
  #pragma unroll
  for (int u2 = 0; u2 < 2; ++u2){
    int cch = 16 + 2 * h + u2;
    bf16x8 vj  = *(const bf16x8*)((char*)&smem[wave][0] + iq * 384 + ((cch ^ (iq & 7)) << 4));
    bf16x8 v16 = *(const bf16x8*)((char*)&smem[wave][0] + 16 * 384 + (cch << 4));
    #pragma unroll
    for (int z = 0; z < 8; ++z){
      float w = wc[h * 16 + u2 * 8 + z];   // transient; L1-broadcast within head group
      vt   += bf2f(vj[z])  * w;
      vt16 += bf2f(v16[z]) * w;
    }
  }

  float part = 0.f;
  #pragma unroll 1
  for (int t = 0; t < 2; ++t){
    const int i = (t == 0) ? iq : 16;    // t=1: ALL lanes compute row 16 (uniform)
    float q[16];
    #pragma unroll
    for (int u2 = 0; u2 < 2; ++u2){
      int cch = 2 * h + u2;
      bf16x8 v = *(const bf16x8*)((char*)&smem[wave][0] + i * 384 + ((cch ^ (i & 7)) << 4));
      #pragma unroll
      for (int z = 0; z < 8; ++z) q[u2 * 8 + z] = bf2f(v[z]);
    }
    // fused softmax-PV: num = sum_j exp(s_j) * vtilde_j ; den = sum_j exp(s_j)
    float num = 0.f, den = 0.f;
    #pragma unroll
    for (int j = 0; j < 17; ++j){
      float a2 = 0.f;
      #pragma unroll
      for (int u2 = 0; u2 < 2; ++u2){
        int cch = 8 + 2 * h + u2;
        bf16x8 v = *(const bf16x8*)((char*)&smem[wave][0] + j * 384 + ((cch ^ (j & 7)) << 4));
        #pragma unroll
        for (int z = 0; z < 8; ++z) a2 += q[u2 * 8 + z] * bf2f(v[z]);
      }
      float e = __expf(a2 * 0.25f);       // 1/sqrt(16); |s| ~ O(1), exp safe
      float vtj = (j < 16) ? __shfl(vt, (lane & 48) + j) : vt16;  // uniform exec
      num += e * vtj;
      den += e;
    }
    float contrib = num / den;
    part += (t == 0 || iq == 0) ? contrib : 0.f;     // predicated, not branched
  }
  // out = lrelu( (1/17) * sum part + bcomb ), reduce over 64 lanes (17 i x 4 h)
  #pragma unroll
  for (int off = 1; off < 64; off <<= 1) part += __shfl_xor(part, off);
  if (lane == 0) out[b] = lrelu(part * (1.f / 17.f) + wc[64]);
}

extern "C" void kernel_launch(void* const* d_in, const int* in_sizes, int n_in,
                              void* d_out, int out_size, void* d_ws, size_t ws_size,
                              hipStream_t stream)
{
  const float* x   = (const float*)d_in[0];
  const float* W1  = (const float*)d_in[1];
  const float* b1  = (const float*)d_in[2];
  const float* Wm  = (const float*)d_in[3];
  const float* bm  = (const float*)d_in[4];
  const float* Wf  = (const float*)d_in[5];
  const float* bf_ = (const float*)d_in[6];
  const float* Wq  = (const float*)d_in[7];
  const float* bq  = (const float*)d_in[8];
  const float* Wk  = (const float*)d_in[9];
  const float* bk  = (const float*)d_in[10];
  const float* Wv  = (const float*)d_in[11];
  const float* bv  = (const float*)d_in[12];
  const float* Wo  = (const float*)d_in[13];
  const float* bo  = (const float*)d_in[14];
  const float* Wfc = (const float*)d_in[15];
  const float* bfc = (const float*)d_in[16];
  float* out = (float*)d_out;
  (void)in_sizes; (void)n_in; (void)out_size; (void)ws_size;

  char* ws = (char*)d_ws;
  size_t off = 0;
  auto alloc = [&](size_t bytes) -> char* {
    char* p = ws + off;
    off = (off + bytes + 255) & ~(size_t)255;
    return p;
  };
  short* qkvb  = (short*)alloc((size_t)B_N * D_N * 192 * 2);      // ~102 MB
  short* WmT   = (short*)alloc((size_t)2 * D_N * H_N * H_N * 2);  // 4.5 MB
  short* WfT   = (short*)alloc((size_t)D_N * E_N * H_N * 2);      // 0.56 MB
  short* Wqkvb = (short*)alloc((size_t)192 * E_N * 2);
  float* wcomb = (float*)alloc(65 * sizeof(float));

  transpose_convert<<<dim3(8, 8, 2 * D_N), dim3(32, 8), 0, stream>>>(Wm, WmT, 256, 256);
  transpose_convert<<<dim3(2, 8, D_N),     dim3(32, 8), 0, stream>>>(Wf, WfT, 256, 64);
  convert_wqkv<<<dim3(48), dim3(256), 0, stream>>>(Wq, Wk, Wv, Wqkvb);
  wcomb_kernel<<<dim3(1), dim3(64), 0, stream>>>(Wo, Wfc, bo, bfc, wcomb);

  subnet_kernel<<<dim3(256 * D_N), dim3(256), 0, stream>>>(
      x, W1, b1, bm, bf_, bq, bk, bv, WmT, WfT, Wqkvb, qkvb);

  attn_kernel<<<dim3(4096), dim3(256), 0, stream>>>(qkvb, wcomb, out);
}

// Round 11
// 415.913 us; speedup vs baseline: 1.9467x; 1.9467x over previous
//
#include <hip/hip_runtime.h>
#include <hip/hip_bf16.h>

#define B_N   16384
#define D_N   17
#define H_N   256
#define E_N   64

typedef __attribute__((ext_vector_type(8))) short bf16x8;
typedef __attribute__((ext_vector_type(4))) float f32x4;

#define WAITV(N) asm volatile("s_waitcnt vmcnt(" #N ")" ::: "memory")
#define WAITL()  asm volatile("s_waitcnt lgkmcnt(0)" ::: "memory")
#define BAR()    __builtin_amdgcn_s_barrier()

static __device__ __forceinline__ short f2bf(float f){
  unsigned u = __builtin_bit_cast(unsigned, f);
  unsigned r = (u + 0x7fffu + ((u >> 16) & 1u)) >> 16;   // RNE
  return (short)(unsigned short)r;
}
static __device__ __forceinline__ float bf2f(short s){
  unsigned u = ((unsigned)(unsigned short)s) << 16;
  return __builtin_bit_cast(float, u);
}
static __device__ __forceinline__ float lrelu(float v){ return fmaxf(v, 0.01f * v); }

// packed f32x2 -> bf16x2 (RNE), 1 instruction; src0 -> low 16, src1 -> high 16
static __device__ __forceinline__ unsigned cvtpk2(float lo, float hi){
  unsigned r;
  asm("v_cvt_pk_bf16_f32 %0, %1, %2" : "=v"(r) : "v"(lo), "v"(hi));
  return r;
}

// async global->LDS, 16B per lane. LDS dest is wave-uniform base + lane*16.
static __device__ __forceinline__ void gload_lds16(const short* g, short* l){
  __builtin_amdgcn_global_load_lds(
      (const __attribute__((address_space(1))) unsigned int*)g,
      (__attribute__((address_space(3))) unsigned int*)l, 16, 0, 0);
}

// ---------- prep: fp32 (G,R,C) -> bf16 (G,C,R) ----------
__global__ void transpose_convert(const float* __restrict__ in, short* __restrict__ outp,
                                  int R, int C){
  __shared__ float tile[32][33];
  int g = blockIdx.z;
  const float* inp = in + (size_t)g * R * C;
  short* op = outp + (size_t)g * R * C;
  int c0 = blockIdx.x * 32, r0 = blockIdx.y * 32;
  for (int i = threadIdx.y; i < 32; i += 8)
    tile[i][threadIdx.x] = inp[(size_t)(r0 + i) * C + c0 + threadIdx.x];
  __syncthreads();
  for (int i = threadIdx.y; i < 32; i += 8)
    op[(size_t)(c0 + i) * R + r0 + threadIdx.x] = f2bf(tile[threadIdx.x][i]);
}

// ---------- prep: stack+convert Wq|Wk|Wv -> bf16 [192][64] ----------
__global__ void convert_wqkv(const float* __restrict__ Wq, const float* __restrict__ Wk,
                             const float* __restrict__ Wv, short* __restrict__ outw){
  int i = blockIdx.x * 256 + threadIdx.x;        // 0..12287
  int g = i >> 12, r = i & 4095;
  const float* W = (g == 0) ? Wq : (g == 1 ? Wk : Wv);
  outw[i] = f2bf(W[r]);
}

// ---------- prep: wcomb[e] = sum_eo Wo[eo][e]*Wfc[eo]; wcomb[64] = bo.Wfc + bfc ----------
__global__ void wcomb_kernel(const float* __restrict__ Wo, const float* __restrict__ Wfc,
                             const float* __restrict__ bo, const float* __restrict__ bfc,
                             float* __restrict__ wcomb){
  int e = threadIdx.x;
  float acc = 0.f;
  for (int eo = 0; eo < 64; ++eo) acc += Wo[eo * 64 + e] * Wfc[eo];
  wcomb[e] = acc;
  if (e == 0){
    float bc = bfc[0];
    for (int eo = 0; eo < 64; ++eo) bc += bo[eo] * Wfc[eo];
    wcomb[64] = bc;
  }
}

// Weight slice staging (256-thr block). Slice kk of [256][256] bf16 = 16 KB
// = 1024 x 16B chunks, 4/thread. Chunk swizzle on the GLOBAL source address
// (gload_lds writes linearly); read XORs the same term.
static __device__ __forceinline__ void stage_w256(const short* Wt, int kk, short* wb,
                                                  int tid, int wave){
  #pragma unroll
  for (int r = 0; r < 4; ++r){
    int li = r * 256 + tid;
    int n  = li >> 2;
    int cc = (li & 3) ^ ((n >> 1) & 3);
    gload_lds16(Wt + n * 256 + kk * 32 + cc * 8,
                wb + (size_t)(r * 256 + wave * 64) * 8);
  }
}
// Full Wf matrix [64][256] = 32 KB into a contiguous region, XOR-16 row swizzle:
// LDS chunk (n, c) holds global k-chunk (c&16)|((c^n)&15).
static __device__ __forceinline__ void stage_wf_all(const short* Wfd, short* region,
                                                    int tid, int wave){
  #pragma unroll
  for (int ld = 0; ld < 8; ++ld){
    int li = ld * 256 + tid;          // 0..2047
    int n  = li >> 5;                 // row 0..63
    int c  = li & 31;
    int kc = (c & 16) | ((c ^ n) & 15);
    gload_lds16(Wfd + n * 256 + kc * 8, region + (size_t)(ld * 256 + wave * 64) * 8);
  }
}

// ---------- main subnet kernel (identical to R9/R10 passing version) ----------
__global__ __launch_bounds__(256, 2) void subnet_kernel(
    const float* __restrict__ x, const float* __restrict__ W1, const float* __restrict__ b1,
    const float* __restrict__ bm, const float* __restrict__ bf_,
    const float* __restrict__ bq, const float* __restrict__ bk, const float* __restrict__ bv,
    const short* __restrict__ WmT, const short* __restrict__ WfT, const short* __restrict__ Wqkv,
    short* __restrict__ qkv)
{
  __shared__ short hbuf[64 * 256];       // 32 KB activations / tokens / qkv-out
  __shared__ short wbuf[3][256 * 32];    // 3 x 16 KB weight slices

  // XCD swizzle: 4352 = 8*544, d-major (per-XCD weight set L2-resident)
  int wg = blockIdx.x;
  int idx = (wg & 7) * 544 + (wg >> 3);
  const int d  = idx >> 8;
  const int m0 = (idx & 255) * 64;

  const int tid = threadIdx.x;
  const int lane = tid & 63, wave = tid >> 6;
  const int l15 = lane & 15, lhi = lane >> 4;

  const short* WtL0 = WmT + (size_t)(0 * D_N + d) * (H_N * H_N);
  const short* WtL1 = WmT + (size_t)(1 * D_N + d) * (H_N * H_N);
  const short* Wfd  = WfT + (size_t)d * (E_N * H_N);

  // prologue: slices 0,1 fly during phase 0
  stage_w256(WtL0, 0, &wbuf[0][0], tid, wave);
  stage_w256(WtL0, 1, &wbuf[1][0], tid, wave);

  // ---- phase 0: h0 = lrelu(x*W1+b1) -> swizzled LDS [m][k], cvt_pk b32 writes
  {
    const int kp = tid & 127;            // k-pair, k0 = 2*kp
    const int mh = tid >> 7;             // 0/1 -> m half
    const float w1a = W1[d * H_N + 2 * kp], w1b = W1[d * H_N + 2 * kp + 1];
    const float b1a = b1[d * H_N + 2 * kp], b1b = b1[d * H_N + 2 * kp + 1];
    #pragma unroll
    for (int i = 0; i < 32; ++i){
      int m = mh * 32 + i;
      float xv = x[(size_t)(m0 + m) * D_N + d];
      unsigned pk = cvtpk2(lrelu(xv * w1a + b1a), lrelu(xv * w1b + b1b));
      int byte = m * 512 + ((((kp >> 2) ^ (m & 7))) << 4) + ((kp & 3) << 2);
      *(unsigned*)((char*)&hbuf[0] + byte) = pk;
    }
  }
  WAITL();   // drain own h0 ds_writes; visibility via first step barrier

  // ---- 2 middle layers: (64x256)@(256x256); wave = 64-col slice; in-place
  for (int L = 0; L < 2; ++L){
    const float* bias = bm + (size_t)(L * D_N + d) * H_N;
    f32x4 acc[4][4];
    #pragma unroll
    for (int a = 0; a < 4; ++a)
      #pragma unroll
      for (int c = 0; c < 4; ++c) acc[a][c] = (f32x4){0.f, 0.f, 0.f, 0.f};

    #pragma unroll
    for (int kk = 0; kk < 8; ++kk){
      const int s = L * 8 + kk;
      if (s == 15) { WAITV(0); } else { WAITV(4); }
      BAR();
      const int s2 = s + 2;
      if (s2 < 8)       stage_w256(WtL0, s2,     &wbuf[s2 % 3][0], tid, wave);
      else if (s2 < 16) stage_w256(WtL1, s2 - 8, &wbuf[s2 % 3][0], tid, wave);
      // s2 >= 16: Wf is bulk-staged at the L1 epilogue

      const short* wb = &wbuf[s % 3][0];
      bf16x8 af[4], bfr[4];
      #pragma unroll
      for (int fr = 0; fr < 4; ++fr){
        int row = fr * 16 + l15;
        int cch = kk * 4 + lhi;
        af[fr] = *(const bf16x8*)((const char*)&hbuf[0] + row * 512 + ((cch ^ (row & 7)) << 4));
      }
      #pragma unroll
      for (int fc = 0; fc < 4; ++fc){
        int n = wave * 64 + fc * 16 + l15;
        bfr[fc] = *(const bf16x8*)((const char*)wb + n * 64 + ((lhi ^ ((n >> 1) & 3)) << 4));
      }
      #pragma unroll
      for (int fr = 0; fr < 4; ++fr)
        #pragma unroll
        for (int fc = 0; fc < 4; ++fc)
          acc[fr][fc] = __builtin_amdgcn_mfma_f32_16x16x32_bf16(af[fr], bfr[fc], acc[fr][fc], 0, 0, 0);
    }
    BAR();   // all waves done reading hbuf + wbuf
    if (L == 1) stage_wf_all(Wfd, &wbuf[1][0], tid, wave);  // 32 KB bulk; epilogue = cover
    // bias + lrelu, cvt_pk pairs, bf16 back in place
    #pragma unroll
    for (int fr = 0; fr < 4; ++fr)
      #pragma unroll
      for (int fc = 0; fc < 4; ++fc){
        int col = wave * 64 + fc * 16 + l15;
        float b = bias[col];
        float v0 = lrelu(acc[fr][fc][0] + b), v1 = lrelu(acc[fr][fc][1] + b);
        float v2 = lrelu(acc[fr][fc][2] + b), v3 = lrelu(acc[fr][fc][3] + b);
        unsigned p01 = cvtpk2(v0, v1), p23 = cvtpk2(v2, v3);
        int r0 = fr * 16 + lhi * 4;
        int cb = (col >> 3), c7 = (col & 7) << 1;
        *(short*)((char*)&hbuf[0] + (r0+0)*512 + ((cb ^ ((r0+0)&7)) << 4) + c7) = (short)(p01 & 0xffff);
        *(short*)((char*)&hbuf[0] + (r0+1)*512 + ((cb ^ ((r0+1)&7)) << 4) + c7) = (short)(p01 >> 16);
        *(short*)((char*)&hbuf[0] + (r0+2)*512 + ((cb ^ ((r0+2)&7)) << 4) + c7) = (short)(p23 & 0xffff);
        *(short*)((char*)&hbuf[0] + (r0+3)*512 + ((cb ^ ((r0+3)&7)) << 4) + c7) = (short)(p23 >> 16);
      }
    WAITL();  // drain own epilogue ds_writes; visibility via next barrier
  }

  // ---- Wf layer: (64x256)@(256x64) + bf, weights fully resident, NO inner barriers
  {
    WAITV(0);   // own Wf bulk loads landed
    BAR();      // everyone's landed; also L1 epilogue visible
    const short* wf = &wbuf[1][0];
    const int r0 = wave * 16;
    f32x4 acc[4];
    #pragma unroll
    for (int fc = 0; fc < 4; ++fc) acc[fc] = (f32x4){0.f, 0.f, 0.f, 0.f};
    #pragma unroll
    for (int kk = 0; kk < 8; ++kk){
      int row = r0 + l15;
      int cch = kk * 4 + lhi;
      bf16x8 a = *(const bf16x8*)((const char*)&hbuf[0] + row * 512 + ((cch ^ (row & 7)) << 4));
      int K = kk * 4 + lhi;
      int c = (K & 16) | ((K ^ l15) & 15);
      #pragma unroll
      for (int fc = 0; fc < 4; ++fc){
        bf16x8 b = *(const bf16x8*)((const char*)wf + (size_t)(fc * 16 + l15) * 512 + c * 16);
        acc[fc] = __builtin_amdgcn_mfma_f32_16x16x32_bf16(a, b, acc[fc], 0, 0, 0);
      }
    }
    BAR();   // all waves done reading hbuf activations before token overlay write
    #pragma unroll
    for (int fc = 0; fc < 4; ++fc){
      int col = fc * 16 + l15;
      float b = bf_[d * E_N + col];
      float v0 = acc[fc][0] + b, v1 = acc[fc][1] + b;
      float v2 = acc[fc][2] + b, v3 = acc[fc][3] + b;
      unsigned p01 = cvtpk2(v0, v1), p23 = cvtpk2(v2, v3);
      int rr = r0 + lhi * 4;
      int cb = (col >> 3), c7 = (col & 7) << 1;
      *(short*)((char*)&hbuf[0] + (rr+0)*128 + ((cb ^ ((rr+0)&7)) << 4) + c7) = (short)(p01 & 0xffff);
      *(short*)((char*)&hbuf[0] + (rr+1)*128 + ((cb ^ ((rr+1)&7)) << 4) + c7) = (short)(p01 >> 16);
      *(short*)((char*)&hbuf[0] + (rr+2)*128 + ((cb ^ ((rr+2)&7)) << 4) + c7) = (short)(p23 & 0xffff);
      *(short*)((char*)&hbuf[0] + (rr+3)*128 + ((cb ^ ((rr+3)&7)) << 4) + c7) = (short)(p23 >> 16);
    }
    WAITL();
    BAR();   // tokens visible to all waves
  }

  // ---- fused QKV: tokens(64x64) @ [Wq|Wk|Wv]^T (64x192); wave = 48-col slice
  {
    f32x4 acc[4][3];
    #pragma unroll
    for (int fr = 0; fr < 4; ++fr)
      #pragma unroll
      for (int fc = 0; fc < 3; ++fc) acc[fr][fc] = (f32x4){0.f, 0.f, 0.f, 0.f};
    #pragma unroll
    for (int kk = 0; kk < 2; ++kk){
      bf16x8 af[4];
      #pragma unroll
      for (int fr = 0; fr < 4; ++fr){
        int row = fr * 16 + l15;
        int cch = kk * 4 + lhi;
        af[fr] = *(const bf16x8*)((const char*)&hbuf[0] + row * 128 + ((cch ^ (row & 7)) << 4));
      }
      bf16x8 bb[3];
      #pragma unroll
      for (int fc = 0; fc < 3; ++fc){
        int n = wave * 48 + fc * 16 + l15;
        bb[fc] = *(const bf16x8*)(Wqkv + (size_t)n * E_N + kk * 32 + lhi * 8);
      }
      #pragma unroll
      for (int fr = 0; fr < 4; ++fr)
        #pragma unroll
        for (int fc = 0; fc < 3; ++fc)
          acc[fr][fc] = __builtin_amdgcn_mfma_f32_16x16x32_bf16(af[fr], bb[fc], acc[fr][fc], 0, 0, 0);
    }
    BAR();   // all token reads done; hbuf reusable as qkv-out staging
    // qkv-out LDS layout: [64 rows][stride 200 shorts] (row = local sample)
    #pragma unroll
    for (int fr = 0; fr < 4; ++fr)
      #pragma unroll
      for (int fc = 0; fc < 3; ++fc){
        int n = wave * 48 + fc * 16 + l15;
        int g = n >> 6, nl = n & 63;
        float bias = (g == 0) ? bq[nl] : (g == 1 ? bk[nl] : bv[nl]);
        #pragma unroll
        for (int j = 0; j < 4; ++j){
          int row = fr * 16 + lhi * 4 + j;
          float v = acc[fr][fc][j] + bias;
          hbuf[row * 200 + n] = (short)(cvtpk2(v, v) & 0xffff);
        }
      }
    WAITL();
    BAR();
    // coalesced b128 out: thread t -> row t>>2, chunks (t&3)+4*rep
    {
      int row = tid >> 2, c4 = tid & 3;
      const short* lsrc = &hbuf[0] + row * 200;
      short* gdst = qkv + ((size_t)(m0 + row) * D_N + d) * 192;
      #pragma unroll
      for (int rep = 0; rep < 6; ++rep){
        int c = c4 + rep * 4;
        bf16x8 v = *(const bf16x8*)(lsrc + c * 8);
        *(bf16x8*)(gdst + c * 8) = v;
      }
    }
  }
}

// ---------- attention + pool + folded head: one wave per sample ----------
// R10 root cause found: __launch_bounds__(256,4) makes hipcc allocate 64
// VGPRs (R2 precedent) -> q[16] etc. spill to scratch -> ~1.6GB of HBM
// scratch traffic (WRITE_SIZE 774MB with a 64KB output). (256,2) caps at
// ~128 VGPRs (R3: subnet got 116-124) -> ~40 live regs fit, zero spill.
__global__ __launch_bounds__(256, 2) void attn_kernel(
    const short* __restrict__ qkv, const float* __restrict__ wc, float* __restrict__ out)
{
  __shared__ short smem[4][17 * 192];     // per-wave sample tile, XOR-swizzled 16B chunks
  const int tid = threadIdx.x, lane = tid & 63, wave = tid >> 6;
  const int h = lane >> 4, iq = lane & 15;

  const int b = blockIdx.x * 4 + wave;
  const short* src = qkv + (size_t)b * (17 * 192);
  for (int g0 = lane; g0 < 408; g0 += 64){
    int i = g0 / 24, c = g0 % 24;
    bf16x8 v = *(const bf16x8*)(src + g0 * 8);
    *(bf16x8*)((char*)&smem[wave][0] + i * 384 + ((c ^ (i & 7)) << 4)) = v;
  }
  // same-wave LDS RAW is in-order; compiler inserts lgkmcnt waits before uses

  // pre-dot: vtilde_j = v_j . wcomb (head h slice). Lane holds j = iq;
  // j = 16 computed redundantly by every lane (lane-local, no shuffle).
  float vt = 0.f, vt16 = 0.f;
  #pragma unroll
  for (int u2 = 0; u2 < 2; ++u2){
    int cch = 16 + 2 * h + u2;
    bf16x8 vj  = *(const bf16x8*)((char*)&smem[wave][0] + iq * 384 + ((cch ^ (iq & 7)) << 4));
    bf16x8 v16 = *(const bf16x8*)((char*)&smem[wave][0] + 16 * 384 + (cch << 4));
    #pragma unroll
    for (int z = 0; z < 8; ++z){
      float w = wc[h * 16 + u2 * 8 + z];   // transient; L1-broadcast within head group
      vt   += bf2f(vj[z])  * w;
      vt16 += bf2f(v16[z]) * w;
    }
  }

  float part = 0.f;
  #pragma unroll 1
  for (int t = 0; t < 2; ++t){
    const int i = (t == 0) ? iq : 16;    // t=1: ALL lanes compute row 16 (uniform)
    float q[16];
    #pragma unroll
    for (int u2 = 0; u2 < 2; ++u2){
      int cch = 2 * h + u2;
      bf16x8 v = *(const bf16x8*)((char*)&smem[wave][0] + i * 384 + ((cch ^ (i & 7)) << 4));
      #pragma unroll
      for (int z = 0; z < 8; ++z) q[u2 * 8 + z] = bf2f(v[z]);
    }
    // fused softmax-PV: num = sum_j exp(s_j) * vtilde_j ; den = sum_j exp(s_j)
    float num = 0.f, den = 0.f;
    #pragma unroll
    for (int j = 0; j < 17; ++j){
      float a2 = 0.f;
      #pragma unroll
      for (int u2 = 0; u2 < 2; ++u2){
        int cch = 8 + 2 * h + u2;
        bf16x8 v = *(const bf16x8*)((char*)&smem[wave][0] + j * 384 + ((cch ^ (j & 7)) << 4));
        #pragma unroll
        for (int z = 0; z < 8; ++z) a2 += q[u2 * 8 + z] * bf2f(v[z]);
      }
      float e = __expf(a2 * 0.25f);       // 1/sqrt(16); |s| ~ O(1), exp safe
      float vtj = (j < 16) ? __shfl(vt, (lane & 48) + j) : vt16;  // uniform exec
      num += e * vtj;
      den += e;
    }
    float contrib = num / den;
    part += (t == 0 || iq == 0) ? contrib : 0.f;     // predicated, not branched
  }
  // out = lrelu( (1/17) * sum part + bcomb ), reduce over 64 lanes (17 i x 4 h)
  #pragma unroll
  for (int off = 1; off < 64; off <<= 1) part += __shfl_xor(part, off);
  if (lane == 0) out[b] = lrelu(part * (1.f / 17.f) + wc[64]);
}

extern "C" void kernel_launch(void* const* d_in, const int* in_sizes, int n_in,
                              void* d_out, int out_size, void* d_ws, size_t ws_size,
                              hipStream_t stream)
{
  const float* x   = (const float*)d_in[0];
  const float* W1  = (const float*)d_in[1];
  const float* b1  = (const float*)d_in[2];
  const float* Wm  = (const float*)d_in[3];
  const float* bm  = (const float*)d_in[4];
  const float* Wf  = (const float*)d_in[5];
  const float* bf_ = (const float*)d_in[6];
  const float* Wq  = (const float*)d_in[7];
  const float* bq  = (const float*)d_in[8];
  const float* Wk  = (const float*)d_in[9];
  const float* bk  = (const float*)d_in[10];
  const float* Wv  = (const float*)d_in[11];
  const float* bv  = (const float*)d_in[12];
  const float* Wo  = (const float*)d_in[13];
  const float* bo  = (const float*)d_in[14];
  const float* Wfc = (const float*)d_in[15];
  const float* bfc = (const float*)d_in[16];
  float* out = (float*)d_out;
  (void)in_sizes; (void)n_in; (void)out_size; (void)ws_size;

  char* ws = (char*)d_ws;
  size_t off = 0;
  auto alloc = [&](size_t bytes) -> char* {
    char* p = ws + off;
    off = (off + bytes + 255) & ~(size_t)255;
    return p;
  };
  short* qkvb  = (short*)alloc((size_t)B_N * D_N * 192 * 2);      // ~102 MB
  short* WmT   = (short*)alloc((size_t)2 * D_N * H_N * H_N * 2);  // 4.5 MB
  short* WfT   = (short*)alloc((size_t)D_N * E_N * H_N * 2);      // 0.56 MB
  short* Wqkvb = (short*)alloc((size_t)192 * E_N * 2);
  float* wcomb = (float*)alloc(65 * sizeof(float));

  transpose_convert<<<dim3(8, 8, 2 * D_N), dim3(32, 8), 0, stream>>>(Wm, WmT, 256, 256);
  transpose_convert<<<dim3(2, 8, D_N),     dim3(32, 8), 0, stream>>>(Wf, WfT, 256, 64);
  convert_wqkv<<<dim3(48), dim3(256), 0, stream>>>(Wq, Wk, Wv, Wqkvb);
  wcomb_kernel<<<dim3(1), dim3(64), 0, stream>>>(Wo, Wfc, bo, bfc, wcomb);

  subnet_kernel<<<dim3(256 * D_N), dim3(256), 0, stream>>>(
      x, W1, b1, bm, bf_, bq, bk, bv, WmT, WfT, Wqkvb, qkvb);

  attn_kernel<<<dim3(4096), dim3(256), 0, stream>>>(qkvb, wcomb, out);
}

// Round 12
// 233.611 us; speedup vs baseline: 3.4659x; 1.7804x over previous
//
#include <hip/hip_runtime.h>
#include <hip/hip_bf16.h>

#define B_N   16384
#define D_N   17
#define H_N   256
#define E_N   64

typedef __attribute__((ext_vector_type(8))) short bf16x8;
typedef __attribute__((ext_vector_type(4))) float f32x4;

#define WAITV(N) asm volatile("s_waitcnt vmcnt(" #N ")" ::: "memory")
#define WAITL()  asm volatile("s_waitcnt lgkmcnt(0)" ::: "memory")
#define BAR()    __builtin_amdgcn_s_barrier()

static __device__ __forceinline__ short f2bf(float f){
  unsigned u = __builtin_bit_cast(unsigned, f);
  unsigned r = (u + 0x7fffu + ((u >> 16) & 1u)) >> 16;   // RNE
  return (short)(unsigned short)r;
}
static __device__ __forceinline__ float bf2f(short s){
  unsigned u = ((unsigned)(unsigned short)s) << 16;
  return __builtin_bit_cast(float, u);
}
static __device__ __forceinline__ float lrelu(float v){ return fmaxf(v, 0.01f * v); }

// async global->LDS, 16B per lane. LDS dest is wave-uniform base + lane*16.
static __device__ __forceinline__ void gload_lds16(const short* g, short* l){
  __builtin_amdgcn_global_load_lds(
      (const __attribute__((address_space(1))) unsigned int*)g,
      (__attribute__((address_space(3))) unsigned int*)l, 16, 0, 0);
}

// ---------- prep: fp32 (G,R,C) -> bf16 (G,C,R) ----------
__global__ void transpose_convert(const float* __restrict__ in, short* __restrict__ outp,
                                  int R, int C){
  __shared__ float tile[32][33];
  int g = blockIdx.z;
  const float* inp = in + (size_t)g * R * C;
  short* op = outp + (size_t)g * R * C;
  int c0 = blockIdx.x * 32, r0 = blockIdx.y * 32;
  for (int i = threadIdx.y; i < 32; i += 8)
    tile[i][threadIdx.x] = inp[(size_t)(r0 + i) * C + c0 + threadIdx.x];
  __syncthreads();
  for (int i = threadIdx.y; i < 32; i += 8)
    op[(size_t)(c0 + i) * R + r0 + threadIdx.x] = f2bf(tile[threadIdx.x][i]);
}

// ---------- prep: stack+convert Wq|Wk|Wv -> bf16 [192][64] ----------
__global__ void convert_wqkv(const float* __restrict__ Wq, const float* __restrict__ Wk,
                             const float* __restrict__ Wv, short* __restrict__ outw){
  int i = blockIdx.x * 256 + threadIdx.x;        // 0..12287
  int g = i >> 12, r = i & 4095;
  const float* W = (g == 0) ? Wq : (g == 1 ? Wk : Wv);
  outw[i] = f2bf(W[r]);
}

// ---------- prep: wcomb[e] = sum_eo Wo[eo][e]*Wfc[eo]; wcomb[64] = bo.Wfc + bfc ----------
__global__ void wcomb_kernel(const float* __restrict__ Wo, const float* __restrict__ Wfc,
                             const float* __restrict__ bo, const float* __restrict__ bfc,
                             float* __restrict__ wcomb){
  int e = threadIdx.x;
  float acc = 0.f;
  for (int eo = 0; eo < 64; ++eo) acc += Wo[eo * 64 + e] * Wfc[eo];
  wcomb[e] = acc;
  if (e == 0){
    float bc = bfc[0];
    for (int eo = 0; eo < 64; ++eo) bc += bo[eo] * Wfc[eo];
    wcomb[64] = bc;
  }
}

// Weight slice staging (256-thr block). Slice kk of [256][256] bf16 = 16 KB
// = 1024 x 16B chunks, 4/thread. Chunk swizzle on the GLOBAL source address
// (gload_lds writes linearly); read XORs the same term -> 2-way banks (free).
static __device__ __forceinline__ void stage_w256(const short* Wt, int kk, short* wb,
                                                  int tid, int wave){
  #pragma unroll
  for (int r = 0; r < 4; ++r){
    int li = r * 256 + tid;
    int n  = li >> 2;
    int cc = (li & 3) ^ ((n >> 1) & 3);
    gload_lds16(Wt + n * 256 + kk * 32 + cc * 8,
                wb + (size_t)(r * 256 + wave * 64) * 8);
  }
}
// 64-row slice (Wf): 256 chunks, 1/thread.
static __device__ __forceinline__ void stage_w64(const short* Wt, int kk, short* wb,
                                                 int tid, int wave){
  int n  = tid >> 2;
  int cc = (tid & 3) ^ ((n >> 1) & 3);
  gload_lds16(Wt + n * 256 + kk * 32 + cc * 8, wb + (size_t)(wave * 64) * 8);
}

// ---------- main subnet kernel (EXACT R7 version: measured 195us, zero spill) ----------
// R11 lesson: the R8 "VALU cut" variant (cvt_pk asm + QKV LDS repack) pushed
// register need past the 128 occupancy boundary -> compiler squeezed+spilled
// (+29MB WRITE) and ran 223us. This R7 form fits at 124 VGPR cleanly.
// Tri-buffered weight slices, depth-2 prefetch, counted vmcnt (never 0 in loop).
// Slice stream s=0..23: L0 0-7, L1 0-7, Wf 0-7; buffer = s%3.
__global__ __launch_bounds__(256, 2) void subnet_kernel(
    const float* __restrict__ x, const float* __restrict__ W1, const float* __restrict__ b1,
    const float* __restrict__ bm, const float* __restrict__ bf_,
    const float* __restrict__ bq, const float* __restrict__ bk, const float* __restrict__ bv,
    const short* __restrict__ WmT, const short* __restrict__ WfT, const short* __restrict__ Wqkv,
    short* __restrict__ qkv)
{
  __shared__ short hbuf[64 * 256];       // 32 KB activations (tokens overlay head)
  __shared__ short wbuf[3][256 * 32];    // 3 x 16 KB weight slices

  // XCD swizzle: 4352 = 8*544, d-major (per-XCD weight set L2-resident)
  int wg = blockIdx.x;
  int idx = (wg & 7) * 544 + (wg >> 3);
  const int d  = idx >> 8;
  const int m0 = (idx & 255) * 64;

  const int tid = threadIdx.x;
  const int lane = tid & 63, wave = tid >> 6;
  const int l15 = lane & 15, lhi = lane >> 4;

  const short* WtL0 = WmT + (size_t)(0 * D_N + d) * (H_N * H_N);
  const short* WtL1 = WmT + (size_t)(1 * D_N + d) * (H_N * H_N);
  const short* Wfd  = WfT + (size_t)d * (E_N * H_N);

  // prologue: slices 0,1 fly during phase 0 (8 outstanding loads/wave)
  stage_w256(WtL0, 0, &wbuf[0][0], tid, wave);
  stage_w256(WtL0, 1, &wbuf[1][0], tid, wave);

  // ---- phase 0: h0 = lrelu(x*W1+b1) -> swizzled LDS [m][k], packed b32 writes
  {
    const int kp = tid & 127;            // k-pair, k0 = 2*kp
    const int mh = tid >> 7;             // 0/1 -> m half
    const float w1a = W1[d * H_N + 2 * kp], w1b = W1[d * H_N + 2 * kp + 1];
    const float b1a = b1[d * H_N + 2 * kp], b1b = b1[d * H_N + 2 * kp + 1];
    #pragma unroll
    for (int i = 0; i < 32; ++i){
      int m = mh * 32 + i;
      float xv = x[(size_t)(m0 + m) * D_N + d];
      unsigned lo = (unsigned short)f2bf(lrelu(xv * w1a + b1a));
      unsigned hi = (unsigned short)f2bf(lrelu(xv * w1b + b1b));
      int byte = m * 512 + ((((kp >> 2) ^ (m & 7))) << 4) + ((kp & 3) << 2);
      *(unsigned*)((char*)&hbuf[0] + byte) = lo | (hi << 16);
    }
  }
  WAITL();   // drain own h0 ds_writes; visibility via first step barrier

  // ---- 2 middle layers: (64x256)@(256x256); wave = 64-col slice; in-place
  for (int L = 0; L < 2; ++L){
    const float* bias = bm + (size_t)(L * D_N + d) * H_N;
    f32x4 acc[4][4];
    #pragma unroll
    for (int a = 0; a < 4; ++a)
      #pragma unroll
      for (int c = 0; c < 4; ++c) acc[a][c] = (f32x4){0.f, 0.f, 0.f, 0.f};

    for (int kk = 0; kk < 8; ++kk){
      const int s = L * 8 + kk;
      // wait for slice s to land (slice s+1 stays in flight), then sync
      if (L == 1 && kk == 7) { WAITV(1); } else { WAITV(4); }
      BAR();
      // issue slice s+2 into its tri-buffer slot
      const int s2 = s + 2;
      if (s2 < 8)       stage_w256(WtL0, s2,     &wbuf[s2 % 3][0], tid, wave);
      else if (s2 < 16) stage_w256(WtL1, s2 - 8, &wbuf[s2 % 3][0], tid, wave);
      else              stage_w64 (Wfd,  s2 - 16,&wbuf[s2 % 3][0], tid, wave);

      const short* wb = &wbuf[s % 3][0];
      bf16x8 af[4], bfr[4];
      #pragma unroll
      for (int fr = 0; fr < 4; ++fr){
        int row = fr * 16 + l15;
        int cch = kk * 4 + lhi;
        af[fr] = *(const bf16x8*)((const char*)&hbuf[0] + row * 512 + ((cch ^ (row & 7)) << 4));
      }
      #pragma unroll
      for (int fc = 0; fc < 4; ++fc){
        int n = wave * 64 + fc * 16 + l15;
        bfr[fc] = *(const bf16x8*)((const char*)wb + n * 64 + ((lhi ^ ((n >> 1) & 3)) << 4));
      }
      #pragma unroll
      for (int fr = 0; fr < 4; ++fr)
        #pragma unroll
        for (int fc = 0; fc < 4; ++fc)
          acc[fr][fc] = __builtin_amdgcn_mfma_f32_16x16x32_bf16(af[fr], bfr[fc], acc[fr][fc], 0, 0, 0);
    }
    BAR();   // all waves done reading hbuf before in-place overwrite
    #pragma unroll
    for (int fr = 0; fr < 4; ++fr)
      #pragma unroll
      for (int fc = 0; fc < 4; ++fc)
        #pragma unroll
        for (int j = 0; j < 4; ++j){
          int row = fr * 16 + lhi * 4 + j;
          int col = wave * 64 + fc * 16 + l15;
          float v = lrelu(acc[fr][fc][j] + bias[col]);
          int byte = row * 512 + ((((col >> 3) ^ (row & 7))) << 4) + ((col & 7) << 1);
          *(short*)((char*)&hbuf[0] + byte) = f2bf(v);
        }
    WAITL();  // drain own epilogue ds_writes; visibility via next step barrier
  }

  // ---- Wf layer: (64x256)@(256x64) + bf -> tokens overlay in hbuf [m][64]
  {
    const int r0 = wave * 16;
    f32x4 acc[4];
    #pragma unroll
    for (int fc = 0; fc < 4; ++fc) acc[fc] = (f32x4){0.f, 0.f, 0.f, 0.f};
    for (int kk = 0; kk < 8; ++kk){
      if (kk == 7) { WAITV(0); } else { WAITV(1); }
      BAR();
      if (kk < 6) stage_w64(Wfd, kk + 2, &wbuf[(18 + kk) % 3][0], tid, wave);
      const short* wb = &wbuf[(16 + kk) % 3][0];
      int row = r0 + l15;
      int cch = kk * 4 + lhi;
      bf16x8 a = *(const bf16x8*)((const char*)&hbuf[0] + row * 512 + ((cch ^ (row & 7)) << 4));
      #pragma unroll
      for (int fc = 0; fc < 4; ++fc){
        int n = fc * 16 + l15;
        bf16x8 b = *(const bf16x8*)((const char*)wb + n * 64 + ((lhi ^ ((n >> 1) & 3)) << 4));
        acc[fc] = __builtin_amdgcn_mfma_f32_16x16x32_bf16(a, b, acc[fc], 0, 0, 0);
      }
    }
    BAR();   // all waves done reading hbuf before token overlay write
    #pragma unroll
    for (int fc = 0; fc < 4; ++fc)
      #pragma unroll
      for (int j = 0; j < 4; ++j){
        int row = r0 + lhi * 4 + j;
        int col = fc * 16 + l15;
        float v = acc[fc][j] + bf_[d * E_N + col];
        int byte = row * 128 + ((((col >> 3) ^ (row & 7))) << 4) + ((col & 7) << 1);
        *(short*)((char*)&hbuf[0] + byte) = f2bf(v);
      }
    WAITL();
    BAR();   // tokens visible to all waves
  }

  // ---- fused QKV: tokens(64x64) @ [Wq|Wk|Wv]^T (64x192); wave = 48-col slice
  // Wqkv is 24KB shared by ALL blocks -> L1/L2-hot; direct global loads fine.
  {
    f32x4 acc[4][3];
    #pragma unroll
    for (int fr = 0; fr < 4; ++fr)
      #pragma unroll
      for (int fc = 0; fc < 3; ++fc) acc[fr][fc] = (f32x4){0.f, 0.f, 0.f, 0.f};
    #pragma unroll
    for (int kk = 0; kk < 2; ++kk){
      bf16x8 af[4];
      #pragma unroll
      for (int fr = 0; fr < 4; ++fr){
        int row = fr * 16 + l15;
        int cch = kk * 4 + lhi;
        af[fr] = *(const bf16x8*)((const char*)&hbuf[0] + row * 128 + ((cch ^ (row & 7)) << 4));
      }
      bf16x8 bb[3];
      #pragma unroll
      for (int fc = 0; fc < 3; ++fc){
        int n = wave * 48 + fc * 16 + l15;
        bb[fc] = *(const bf16x8*)(Wqkv + (size_t)n * E_N + kk * 32 + lhi * 8);
      }
      #pragma unroll
      for (int fr = 0; fr < 4; ++fr)
        #pragma unroll
        for (int fc = 0; fc < 3; ++fc)
          acc[fr][fc] = __builtin_amdgcn_mfma_f32_16x16x32_bf16(af[fr], bb[fc], acc[fr][fc], 0, 0, 0);
    }
    #pragma unroll
    for (int fr = 0; fr < 4; ++fr)
      #pragma unroll
      for (int fc = 0; fc < 3; ++fc)
        #pragma unroll
        for (int j = 0; j < 4; ++j){
          int n = wave * 48 + fc * 16 + l15;
          int g = n >> 6, nl = n & 63;
          float bias = (g == 0) ? bq[nl] : (g == 1 ? bk[nl] : bv[nl]);
          int bg = m0 + fr * 16 + lhi * 4 + j;
          float v = acc[fr][fc][j] + bias;
          qkv[((size_t)bg * D_N + d) * 192 + n] = f2bf(v);
        }
  }
}

// ---------- attention + pool + folded head: one wave per sample ----------
// R11 lesson: the fully-unrolled 17-iter j-loop let the scheduler hoist up to
// 34 ds_read results (136 VGPRs in flight) -> squeezed to 128 and spilled
// (WRITE 250MB). Fix: #pragma unroll 1 on the j-loop (<=2 loads in flight),
// j=16 handled separately (uniform, no per-iter select). Live set ~50 regs.
// TLP covers the serialized LDS latency (26KB LDS -> 6 blocks/CU).
__global__ __launch_bounds__(256, 2) void attn_kernel(
    const short* __restrict__ qkv, const float* __restrict__ wc, float* __restrict__ out)
{
  __shared__ short smem[4][17 * 192];     // per-wave sample tile, XOR-swizzled 16B chunks
  const int tid = threadIdx.x, lane = tid & 63, wave = tid >> 6;
  const int h = lane >> 4, iq = lane & 15;

  const int b = blockIdx.x * 4 + wave;
  const short* src = qkv + (size_t)b * (17 * 192);
  for (int g0 = lane; g0 < 408; g0 += 64){
    int i = g0 / 24, c = g0 % 24;
    bf16x8 v = *(const bf16x8*)(src + g0 * 8);
    *(bf16x8*)((char*)&smem[wave][0] + i * 384 + ((c ^ (i & 7)) << 4)) = v;
  }
  // same-wave LDS RAW is in-order; compiler inserts lgkmcnt waits before uses

  // pre-dot: vtilde_j = v_j . wcomb (head h slice). Lane holds j = iq;
  // j = 16 computed redundantly by every lane (lane-local, no shuffle).
  float vt = 0.f, vt16 = 0.f;
  #pragma unroll
  for (int u2 = 0; u2 < 2; ++u2){
    int cch = 16 + 2 * h + u2;
    bf16x8 vj  = *(const bf16x8*)((char*)&smem[wave][0] + iq * 384 + ((cch ^ (iq & 7)) << 4));
    bf16x8 v16 = *(const bf16x8*)((char*)&smem[wave][0] + 16 * 384 + (cch << 4));
    #pragma unroll
    for (int z = 0; z < 8; ++z){
      float w = wc[h * 16 + u2 * 8 + z];   // transient; L1-broadcast within head group
      vt   += bf2f(vj[z])  * w;
      vt16 += bf2f(v16[z]) * w;
    }
  }

  float part = 0.f;
  #pragma unroll 1
  for (int t = 0; t < 2; ++t){
    const int i = (t == 0) ? iq : 16;    // t=1: ALL lanes compute row 16 (uniform)
    float q[16];
    #pragma unroll
    for (int u2 = 0; u2 < 2; ++u2){
      int cch = 2 * h + u2;
      bf16x8 v = *(const bf16x8*)((char*)&smem[wave][0] + i * 384 + ((cch ^ (i & 7)) << 4));
      #pragma unroll
      for (int z = 0; z < 8; ++z) q[u2 * 8 + z] = bf2f(v[z]);
    }
    // fused softmax-PV: num = sum_j exp(s_j)*vtilde_j ; den = sum_j exp(s_j)
    float num = 0.f, den = 0.f;
    #pragma unroll 1                      // cap in-flight LDS loads / live range
    for (int j = 0; j < 16; ++j){
      float a2 = 0.f;
      #pragma unroll
      for (int u2 = 0; u2 < 2; ++u2){
        int cch = 8 + 2 * h + u2;
        bf16x8 v = *(const bf16x8*)((char*)&smem[wave][0] + j * 384 + ((cch ^ (j & 7)) << 4));
        #pragma unroll
        for (int z = 0; z < 8; ++z) a2 += q[u2 * 8 + z] * bf2f(v[z]);
      }
      float e = __expf(a2 * 0.25f);       // 1/sqrt(16); |s| ~ O(1), exp safe
      num += e * __shfl(vt, (lane & 48) + j);   // uniform: all 64 lanes active
      den += e;
    }
    {  // j = 16 (row swizzle term is 0 since 16&7 == 0)
      float a2 = 0.f;
      #pragma unroll
      for (int u2 = 0; u2 < 2; ++u2){
        int cch = 8 + 2 * h + u2;
        bf16x8 v = *(const bf16x8*)((char*)&smem[wave][0] + 16 * 384 + (cch << 4));
        #pragma unroll
        for (int z = 0; z < 8; ++z) a2 += q[u2 * 8 + z] * bf2f(v[z]);
      }
      float e = __expf(a2 * 0.25f);
      num += e * vt16;
      den += e;
    }
    float contrib = num / den;
    part += (t == 0 || iq == 0) ? contrib : 0.f;     // predicated, not branched
  }
  // out = lrelu( (1/17) * sum part + bcomb ), reduce over 64 lanes (17 i x 4 h)
  #pragma unroll
  for (int off = 1; off < 64; off <<= 1) part += __shfl_xor(part, off);
  if (lane == 0) out[b] = lrelu(part * (1.f / 17.f) + wc[64]);
}

extern "C" void kernel_launch(void* const* d_in, const int* in_sizes, int n_in,
                              void* d_out, int out_size, void* d_ws, size_t ws_size,
                              hipStream_t stream)
{
  const float* x   = (const float*)d_in[0];
  const float* W1  = (const float*)d_in[1];
  const float* b1  = (const float*)d_in[2];
  const float* Wm  = (const float*)d_in[3];
  const float* bm  = (const float*)d_in[4];
  const float* Wf  = (const float*)d_in[5];
  const float* bf_ = (const float*)d_in[6];
  const float* Wq  = (const float*)d_in[7];
  const float* bq  = (const float*)d_in[8];
  const float* Wk  = (const float*)d_in[9];
  const float* bk  = (const float*)d_in[10];
  const float* Wv  = (const float*)d_in[11];
  const float* bv  = (const float*)d_in[12];
  const float* Wo  = (const float*)d_in[13];
  const float* bo  = (const float*)d_in[14];
  const float* Wfc = (const float*)d_in[15];
  const float* bfc = (const float*)d_in[16];
  float* out = (float*)d_out;
  (void)in_sizes; (void)n_in; (void)out_size; (void)ws_size;

  char* ws = (char*)d_ws;
  size_t off = 0;
  auto alloc = [&](size_t bytes) -> char* {
    char* p = ws + off;
    off = (off + bytes + 255) & ~(size_t)255;
    return p;
  };
  short* qkvb  = (short*)alloc((size_t)B_N * D_N * 192 * 2);      // ~102 MB
  short* WmT   = (short*)alloc((size_t)2 * D_N * H_N * H_N * 2);  // 4.5 MB
  short* WfT   = (short*)alloc((size_t)D_N * E_N * H_N * 2);      // 0.56 MB
  short* Wqkvb = (short*)alloc((size_t)192 * E_N * 2);
  float* wcomb = (float*)alloc(65 * sizeof(float));

  transpose_convert<<<dim3(8, 8, 2 * D_N), dim3(32, 8), 0, stream>>>(Wm, WmT, 256, 256);
  transpose_convert<<<dim3(2, 8, D_N),     dim3(32, 8), 0, stream>>>(Wf, WfT, 256, 64);
  convert_wqkv<<<dim3(48), dim3(256), 0, stream>>>(Wq, Wk, Wv, Wqkvb);
  wcomb_kernel<<<dim3(1), dim3(64), 0, stream>>>(Wo, Wfc, bo, bfc, wcomb);

  subnet_kernel<<<dim3(256 * D_N), dim3(256), 0, stream>>>(
      x, W1, b1, bm, bf_, bq, bk, bv, WmT, WfT, Wqkvb, qkvb);

  attn_kernel<<<dim3(4096), dim3(256), 0, stream>>>(qkvb, wcomb, out);
}